// Round 1
// baseline (202.698 us; speedup 1.0000x reference)
//
#include <hip/hip_runtime.h>
#include <hip/hip_bf16.h>
#include <cstddef>

#define SNL_N 50000
#define SNL_K 32
#define SNL_D 128
#define SNL_EPS 1e-12f

// One 64-lane wave handles 2 consecutive rows: lane = (half<<5)|k, half -> row r0+half.
// Each lane owns one (row, k): gathers anchor row with float4 loop, d2 stays in-register.
// Softmax over k = 32-lane butterfly (masks 1..16 stay within the half).
// 6250 blocks x 256 threads (4 waves) = 8 rows/block, 50000 exactly -> no guards.
__global__ __launch_bounds__(256) void snl_main(const float* __restrict__ emb,
                                                const float* __restrict__ psim,
                                                const int* __restrict__ aidx,
                                                float* __restrict__ out,
                                                float* __restrict__ part) {
    const int tid  = threadIdx.x;
    const int wid  = tid >> 6;       // wave in block (0..3)
    const int lane = tid & 63;
    const int half = lane >> 5;      // which of the wave's 2 rows
    const int r0   = (blockIdx.x * 4 + wid) * 2;   // first row of this wave

    __shared__ float yibuf[4][2 * SNL_D];   // 2 rows of yi per wave
    __shared__ float bred[4];

    // Stage yi for both rows: 256 floats, coalesced 16B/lane.
    {
        const float4* src = reinterpret_cast<const float4*>(emb + (size_t)r0 * SNL_D);
        reinterpret_cast<float4*>(&yibuf[wid][0])[lane] = src[lane];
    }
    __syncthreads();

    // This lane's anchor: aidx[r*K + k] == aidx[r0*K + lane] -> coalesced.
    const int a = aidx[(size_t)r0 * SNL_K + lane];
    const float4* jrow = reinterpret_cast<const float4*>(emb + (size_t)a * SNL_D);
    const float4* irow = reinterpret_cast<const float4*>(&yibuf[wid][half * SNL_D]);

    float d2 = 0.0f;
#pragma unroll
    for (int d4 = 0; d4 < SNL_D / 4; ++d4) {
        float4 yj = jrow[d4];
        float4 yi = irow[d4];
        float dx = yi.x - yj.x;
        float dy = yi.y - yj.y;
        float dz = yi.z - yj.z;
        float dw = yi.w - yj.w;
        d2 = fmaf(dx, dx, d2);
        d2 = fmaf(dy, dy, d2);
        d2 = fmaf(dz, dz, d2);
        d2 = fmaf(dw, dw, d2);
    }

    const float s = -d2;   // logit

    // max over the 32 k-lanes of this half
    float m = s;
#pragma unroll
    for (int off = 1; off < 32; off <<= 1)
        m = fmaxf(m, __shfl_xor(m, off, 64));

    const float e = expf(s - m);
    float ss = e;
#pragma unroll
    for (int off = 1; off < 32; off <<= 1)
        ss += __shfl_xor(ss, off, 64);

    const float logq = (s - m) - logf(ss);
    const float q    = e / ss;

    // q store: out[1 + r*K + k] == out + 1 + r0*K + lane -> coalesced
    out[1 + (size_t)r0 * SNL_K + lane] = q;

    // loss term (flat sum over all (i,k) -- no per-row reduce needed)
    const float pv   = psim[(size_t)r0 * SNL_K + lane];
    const float term = pv * (logf(pv + SNL_EPS) - logq);

    // block reduction of loss partial
    float acc = term;
#pragma unroll
    for (int off = 1; off < 64; off <<= 1)
        acc += __shfl_xor(acc, off, 64);
    if (lane == 0) bred[wid] = acc;
    __syncthreads();
    if (tid == 0) part[blockIdx.x] = bred[0] + bred[1] + bred[2] + bred[3];
}

__global__ __launch_bounds__(256) void snl_loss_reduce(const float* __restrict__ part,
                                                       int npart,
                                                       float* __restrict__ out) {
    double acc = 0.0;
    for (int i = threadIdx.x; i < npart; i += 256) acc += (double)part[i];
#pragma unroll
    for (int off = 1; off < 64; off <<= 1)
        acc += __shfl_xor(acc, off, 64);
    __shared__ double sred[4];
    if ((threadIdx.x & 63) == 0) sred[threadIdx.x >> 6] = acc;
    __syncthreads();
    if (threadIdx.x == 0)
        out[0] = (float)((sred[0] + sred[1] + sred[2] + sred[3]) / (double)SNL_N);
}

extern "C" void kernel_launch(void* const* d_in, const int* in_sizes, int n_in,
                              void* d_out, int out_size, void* d_ws, size_t ws_size,
                              hipStream_t stream) {
    const float* emb  = (const float*)d_in[0];
    const float* psim = (const float*)d_in[1];
    const int*   aidx = (const int*)d_in[2];
    float* out  = (float*)d_out;
    float* part = (float*)d_ws;   // 6250 floats = 25 KB

    const int nblocks = SNL_N / 8;   // 6250, exact
    snl_main<<<nblocks, 256, 0, stream>>>(emb, psim, aidx, out, part);
    snl_loss_reduce<<<1, 256, 0, stream>>>(part, nblocks, out);
}

// Round 2
// 177.571 us; speedup vs baseline: 1.1415x; 1.1415x over previous
//
#include <hip/hip_runtime.h>
#include <hip/hip_bf16.h>
#include <cstddef>

#define SNL_N 50000
#define SNL_K 32
#define SNL_D 128
#define SNL_EPS 1e-12f
#define SNL_GROUPS (SNL_N / 4)   // 12500 groups of 4 rows (one row per wave)
#define SNL_GRID 2048            // grid-stride; 8 blocks/CU on 256 CUs

// One wave per row i. lane = asub*8 + dc: asub = which of 8 anchors in the
// current group-of-8, dc = which 16B chunk of the 512B row. Each wave-level
// load touches 8 rows x 1 full 128B line = 8 transactions (vs 64 in the
// per-lane-gather layout). d2 partial reduced over dc (3 shuffles), then a
// 4-shuffle transpose places d2[k] on lane k for the 32-lane softmax.
__global__ __launch_bounds__(256) void snl_main(const float* __restrict__ emb,
                                                const float* __restrict__ psim,
                                                const int* __restrict__ aidx,
                                                float* __restrict__ out,
                                                float* __restrict__ part) {
    const int tid  = threadIdx.x;
    const int wid  = tid >> 6;       // wave in block -> row within group
    const int lane = tid & 63;
    const int dc   = lane & 7;       // 16B chunk index (0..7) -> 128B line
    const int asub = lane >> 3;      // anchor-in-group (0..7)

    const float4* emb4 = reinterpret_cast<const float4*>(emb);

    float loss_acc = 0.0f;

    for (int grp = blockIdx.x; grp < SNL_GROUPS; grp += gridDim.x) {
        const int i = grp * 4 + wid;

        // yi: 4 float4 chunks per lane (same addr for all asub -> broadcast)
        float4 yir[4];
#pragma unroll
        for (int it = 0; it < 4; ++it)
            yir[it] = emb4[(size_t)i * 32 + dc + it * 8];

        float d2g[4];
#pragma unroll
        for (int g = 0; g < 4; ++g) {
            const int a = aidx[(size_t)i * SNL_K + g * 8 + asub];
            const float4* jr = emb4 + (size_t)a * 32;
            float acc = 0.0f;
#pragma unroll
            for (int it = 0; it < 4; ++it) {
                float4 yj = jr[dc + it * 8];   // 8 lanes cover one 128B line
                float dx = yir[it].x - yj.x;
                float dy = yir[it].y - yj.y;
                float dz = yir[it].z - yj.z;
                float dw = yir[it].w - yj.w;
                acc = fmaf(dx, dx, acc);
                acc = fmaf(dy, dy, acc);
                acc = fmaf(dz, dz, acc);
                acc = fmaf(dw, dw, acc);
            }
            // reduce over the 8 dc-lanes (low 3 bits of lane)
            acc += __shfl_xor(acc, 1, 64);
            acc += __shfl_xor(acc, 2, 64);
            acc += __shfl_xor(acc, 4, 64);
            d2g[g] = acc;   // all 8 lanes of group (g, asub) hold d2
        }

        // transpose: lane k (and its mirror k+32) gets d2 of anchor k
        const int src = (lane & 7) * 8;
        float t0 = __shfl(d2g[0], src, 64);
        float t1 = __shfl(d2g[1], src, 64);
        float t2 = __shfl(d2g[2], src, 64);
        float t3 = __shfl(d2g[3], src, 64);
        const int gsel = (lane >> 3) & 3;
        float d2 = (gsel == 0) ? t0 : (gsel == 1) ? t1 : (gsel == 2) ? t2 : t3;

        // 32-lane softmax (halves are xor-independent for offsets 1..16)
        const float s = -d2;
        float m = s;
#pragma unroll
        for (int off = 1; off < 32; off <<= 1)
            m = fmaxf(m, __shfl_xor(m, off, 64));
        const float e = expf(s - m);
        float ss = e;
#pragma unroll
        for (int off = 1; off < 32; off <<= 1)
            ss += __shfl_xor(ss, off, 64);
        const float logq = (s - m) - logf(ss);
        const float q = e / ss;

        if (lane < SNL_K) {
            out[1 + (size_t)i * SNL_K + lane] = q;      // coalesced 128B store
            const float pv = psim[(size_t)i * SNL_K + lane];
            loss_acc += pv * (logf(pv + SNL_EPS) - logq);
        }
    }

    // block reduction of loss partial
#pragma unroll
    for (int off = 1; off < 64; off <<= 1)
        loss_acc += __shfl_xor(loss_acc, off, 64);

    __shared__ float bred[4];
    if (lane == 0) bred[wid] = loss_acc;
    __syncthreads();
    if (tid == 0) part[blockIdx.x] = bred[0] + bred[1] + bred[2] + bred[3];
}

__global__ __launch_bounds__(256) void snl_loss_reduce(const float* __restrict__ part,
                                                       int npart,
                                                       float* __restrict__ out) {
    double acc = 0.0;
    for (int i = threadIdx.x; i < npart; i += 256) acc += (double)part[i];
#pragma unroll
    for (int off = 1; off < 64; off <<= 1)
        acc += __shfl_xor(acc, off, 64);
    __shared__ double sred[4];
    if ((threadIdx.x & 63) == 0) sred[threadIdx.x >> 6] = acc;
    __syncthreads();
    if (threadIdx.x == 0)
        out[0] = (float)((sred[0] + sred[1] + sred[2] + sred[3]) / (double)SNL_N);
}

extern "C" void kernel_launch(void* const* d_in, const int* in_sizes, int n_in,
                              void* d_out, int out_size, void* d_ws, size_t ws_size,
                              hipStream_t stream) {
    const float* emb  = (const float*)d_in[0];
    const float* psim = (const float*)d_in[1];
    const int*   aidx = (const int*)d_in[2];
    float* out  = (float*)d_out;
    float* part = (float*)d_ws;   // SNL_GRID floats = 8 KB

    snl_main<<<SNL_GRID, 256, 0, stream>>>(emb, psim, aidx, out, part);
    snl_loss_reduce<<<1, 256, 0, stream>>>(part, SNL_GRID, out);
}